// Round 3
// baseline (378.100 us; speedup 1.0000x reference)
//
#include <hip/hip_runtime.h>
#include <math.h>

// Problem constants (fixed by setup_inputs): B=16, T=4096, D=512, fp32.
#define BB 16
#define TT 4096
#define DD 512
#define D4 128   // DD / 4 (float4 columns)
#define CC 128   // time chunks
#define LL 32    // TT / CC timesteps per chunk
#define LH 16    // half chunk
#define TILE_B 65536  // 64 KB LDS tile: one (b, chunk) = 32 t x 512 f x 4 B (contiguous in x)

// ws layout (bytes): [0..4) ticket | [256..256+4*BB*CC) flags | [16384..) ends (4 MB)
#define FLAGS_OFF_U32 64
#define ENDS_OFF_B    16384

typedef float v4f __attribute__((ext_vector_type(4)));
typedef const __attribute__((address_space(1))) unsigned int gua_t;
typedef __attribute__((address_space(3))) unsigned int lua_t;

__device__ __forceinline__ float sigmf(float v) {
    return 1.0f / (1.0f + expf(-v));
}

// out is write-once/never-read: NT store keeps it from evicting x from L3.
__device__ __forceinline__ void nt_store4(float4* p, const float4& s) {
    __builtin_nontemporal_store(*reinterpret_cast<const v4f*>(&s),
                                reinterpret_cast<v4f*>(p));
}

// Async global->LDS, 16 B per lane. LDS dest is wave-uniform base + lane*16 (HW).
__device__ __forceinline__ void gload_lds16(const void* g, void* l) {
    __builtin_amdgcn_global_load_lds((gua_t*)g, (lua_t*)l, 16, 0, 0);
}

// Single-pass chained scan, chunk staged in LDS (no VGPR payload -> no spill).
// Grid: CC*BB blocks, 256 threads = 2 time-halves x 128 float4 columns.
// Ticket -> (b, c): chunk order == start order -> spins only on earlier tickets
// (resident or finished) -> no deadlock regardless of HW dispatch order.
__global__ __launch_bounds__(256) void es_fused(
    const float* __restrict__ x, const float* __restrict__ alpha,
    unsigned int* __restrict__ hdr, float* __restrict__ out)
{
    extern __shared__ char smem[];   // TILE_B bytes
    const int tid  = threadIdx.x;
    const int wave = tid >> 6;
    const int lane = tid & 63;

    // Ticket broadcast through the tile LDS (tile not yet staged).
    if (tid == 0) *((unsigned int*)smem) = atomicAdd(hdr, 1u);
    __syncthreads();
    const unsigned int tk = *((const unsigned int*)smem);
    __syncthreads();                 // everyone read ticket before staging overwrites smem

    const int b = (int)(tk & (BB - 1));
    const int c = (int)(tk >> 4);

    const int th = tid >> 7;         // 0 = t 0..15, 1 = t 16..31
    const int d4 = tid & 127;

    unsigned int* flags = hdr + FLAGS_OFF_U32;
    float4* ends = reinterpret_cast<float4*>(reinterpret_cast<char*>(hdr) + ENDS_OFF_B);

    // ---- Stage the whole 64 KB chunk (contiguous in x) via global_load_lds.
    // 4 waves x 16 segments x 1 KB. Deep async queue: 16 KB in flight per wave.
    {
        const char* gbase = (const char*)x
                          + ((size_t)b * TT + (size_t)c * LL) * (DD * sizeof(float));
        #pragma unroll
        for (int k = 0; k < 16; ++k) {
            const int seg = (wave << 4) + k;         // 0..63
            gload_lds16(gbase + (size_t)seg * 1024 + (size_t)lane * 16,
                        smem + (size_t)seg * 1024);
        }
    }

    // Overlap scalar math with staging latency.
    const float4 al = reinterpret_cast<const float4*>(alpha)[d4];
    const float ax = sigmf(al.x), ay = sigmf(al.y), az = sigmf(al.z), aw = sigmf(al.w);
    const float fx = 1.0f - ax, fy = 1.0f - ay, fz = 1.0f - az, fw = 1.0f - aw;
    float4 fL, fH;
    fL.x = powf(fx, (float)LL); fL.y = powf(fy, (float)LL);
    fL.z = powf(fz, (float)LL); fL.w = powf(fw, (float)LL);
    fH.x = powf(fx, (float)LH); fH.y = powf(fy, (float)LH);
    fH.z = powf(fz, (float)LH); fH.w = powf(fw, (float)LH);

    __syncthreads();   // compiler emits vmcnt(0) before barrier -> tile fully staged

    // LDS address for (timestep tt, column d4): linear layout, conflict-free.
    const char* sbase = smem + (size_t)d4 * 16;
    #define LDS_AT(tt) (*reinterpret_cast<const float4*>(sbase + (size_t)(tt) * 2048))

    // ---- Zero-init local scan. Both halves scan t 0..15 (hi duplicates lo's
    // prefix so no cross-wave exchange is needed); lo continues to the full
    // chunk end E_c (bit-identical FMA order to the previous passing kernels).
    float4 sE;
    if (c == 0) { sE = LDS_AT(0); }  // virtual s_{-1} = x_0 -> E_0 exact
    else        { sE.x = sE.y = sE.z = sE.w = 0.0f; }
    #pragma unroll
    for (int i = 0; i < LH; ++i) {
        const float4 v = LDS_AT(i);
        sE.x = fmaf(ax, v.x, fx * sE.x);
        sE.y = fmaf(ay, v.y, fy * sE.y);
        sE.z = fmaf(az, v.z, fz * sE.z);
        sE.w = fmaf(aw, v.w, fw * sE.w);
    }
    const float4 loE = sE;           // zero-init state after t=15 (exact for c==0)
    if (th == 0) {
        #pragma unroll
        for (int i = LH; i < LL; ++i) {
            const float4 v = LDS_AT(i);
            sE.x = fmaf(ax, v.x, fx * sE.x);
            sE.y = fmaf(ay, v.y, fy * sE.y);
            sE.z = fmaf(az, v.z, fz * sE.z);
            sE.w = fmaf(aw, v.w, fw * sE.w);
        }
        ends[((size_t)b * CC + c) * D4 + d4] = sE;   // full-chunk E_c
    }

    // All E stores drained (barrier implies per-thread vmcnt(0)) before publish.
    __syncthreads();
    if (tid == 0) {
        __hip_atomic_store(&flags[(b << 7) + c], 1u,
                           __ATOMIC_RELEASE, __HIP_MEMORY_SCOPE_AGENT);
    }

    // ---- Lookback: wait for all predecessors, then scan their E's (ascending,
    // same FMA order as before -> carry S_{c-1} bit-identical).
    float4 S; S.x = S.y = S.z = S.w = 0.0f;
    if (c > 0) {
        if (tid < c) {
            while (__hip_atomic_load(&flags[(b << 7) + tid],
                                     __ATOMIC_RELAXED, __HIP_MEMORY_SCOPE_AGENT) == 0u) {
                __builtin_amdgcn_s_sleep(2);
            }
        }
        __syncthreads();
        __builtin_amdgcn_fence(__ATOMIC_ACQUIRE, "agent");

        const float4* e = ends + (size_t)b * CC * D4 + d4;
        S = e[0];
        int j = 1;
        for (; j + 4 <= c; j += 4) {
            float4 v0 = e[(size_t)(j + 0) * D4];
            float4 v1 = e[(size_t)(j + 1) * D4];
            float4 v2 = e[(size_t)(j + 2) * D4];
            float4 v3 = e[(size_t)(j + 3) * D4];
            S.x = fmaf(fL.x, S.x, v0.x); S.y = fmaf(fL.y, S.y, v0.y);
            S.z = fmaf(fL.z, S.z, v0.z); S.w = fmaf(fL.w, S.w, v0.w);
            S.x = fmaf(fL.x, S.x, v1.x); S.y = fmaf(fL.y, S.y, v1.y);
            S.z = fmaf(fL.z, S.z, v1.z); S.w = fmaf(fL.w, S.w, v1.w);
            S.x = fmaf(fL.x, S.x, v2.x); S.y = fmaf(fL.y, S.y, v2.y);
            S.z = fmaf(fL.z, S.z, v2.z); S.w = fmaf(fL.w, S.w, v2.w);
            S.x = fmaf(fL.x, S.x, v3.x); S.y = fmaf(fL.y, S.y, v3.y);
            S.z = fmaf(fL.z, S.z, v3.z); S.w = fmaf(fL.w, S.w, v3.w);
        }
        for (; j < c; ++j) {
            const float4 v = e[(size_t)j * D4];
            S.x = fmaf(fL.x, S.x, v.x);
            S.y = fmaf(fL.y, S.y, v.y);
            S.z = fmaf(fL.z, S.z, v.z);
            S.w = fmaf(fL.w, S.w, v.w);
        }
    }

    // ---- Replay from the exact carry, reading the tile from LDS; NT store out.
    // lo half: init S (identical to previous kernels). hi half: init = exact
    // state after t=15 = loE + f^16 * S (one reassociation, ulp-level delta).
    float4 s;
    if (th == 0) {
        if (c == 0) s = LDS_AT(0); else s = S;
    } else {
        if (c == 0) { s = loE; }
        else {
            s.x = fmaf(fH.x, S.x, loE.x);
            s.y = fmaf(fH.y, S.y, loE.y);
            s.z = fmaf(fH.z, S.z, loE.z);
            s.w = fmaf(fH.w, S.w, loE.w);
        }
    }
    const int t0 = th * LH;
    float4* op = reinterpret_cast<float4*>(out)
               + ((size_t)b * TT + (size_t)c * LL + t0) * D4 + d4;
    #pragma unroll
    for (int i = 0; i < LH; ++i) {
        const float4 v = LDS_AT(t0 + i);
        s.x = fmaf(ax, v.x, fx * s.x);
        s.y = fmaf(ay, v.y, fy * s.y);
        s.z = fmaf(az, v.z, fz * s.z);
        s.w = fmaf(aw, v.w, fw * s.w);
        nt_store4(op + (size_t)i * D4, s);
    }
    #undef LDS_AT
}

// Fallback: full serial scan per (b, d4) column if ws is too small.
__global__ __launch_bounds__(256) void es_serial(
    const float* __restrict__ x, const float* __restrict__ alpha,
    float* __restrict__ out)
{
    const int g  = blockIdx.x * 256 + threadIdx.x;   // 0..2047
    const int b  = g >> 7;
    const int d4 = g & 127;

    const float4 al = reinterpret_cast<const float4*>(alpha)[d4];
    const float ax = sigmf(al.x), ay = sigmf(al.y), az = sigmf(al.z), aw = sigmf(al.w);
    const float fx = 1.0f - ax, fy = 1.0f - ay, fz = 1.0f - az, fw = 1.0f - aw;

    const float4* xp = reinterpret_cast<const float4*>(x) + (size_t)b * TT * D4 + d4;
    float4*       op = reinterpret_cast<float4*>(out) + (size_t)b * TT * D4 + d4;

    float4 s = xp[0];
    #pragma unroll 4
    for (int t = 0; t < TT; ++t) {
        const float4 v = xp[(size_t)t * D4];
        s.x = fmaf(ax, v.x, fx * s.x);
        s.y = fmaf(ay, v.y, fy * s.y);
        s.z = fmaf(az, v.z, fz * s.z);
        s.w = fmaf(aw, v.w, fw * s.w);
        op[(size_t)t * D4] = s;
    }
}

extern "C" void kernel_launch(void* const* d_in, const int* in_sizes, int n_in,
                              void* d_out, int out_size, void* d_ws, size_t ws_size,
                              hipStream_t stream)
{
    const float* x     = (const float*)d_in[0];
    const float* alpha = (const float*)d_in[1];
    float*       out   = (float*)d_out;

    const size_t need = (size_t)ENDS_OFF_B + (size_t)BB * CC * DD * sizeof(float);
    if (ws_size < need) {
        es_serial<<<dim3(8), 256, 0, stream>>>(x, alpha, out);
        return;
    }

    // Zero ticket + flags (16 KB). Graph-capturable async op.
    hipMemsetAsync(d_ws, 0, ENDS_OFF_B, stream);

    es_fused<<<dim3(CC * BB), 256, TILE_B, stream>>>(
        x, alpha, (unsigned int*)d_ws, out);
}

// Round 4
// 258.773 us; speedup vs baseline: 1.4611x; 1.4611x over previous
//
#include <hip/hip_runtime.h>
#include <math.h>

// Problem constants (fixed by setup_inputs): B=16, T=4096, D=512, fp32.
#define BB 16
#define TT 4096
#define DD 512
#define D4 128   // DD / 4 (float4 columns)
#define CC 128   // time chunks
#define LL 32    // TT / CC

typedef float v4f __attribute__((ext_vector_type(4)));

__device__ __forceinline__ float sigmf(float v) {
    return 1.0f / (1.0f + expf(-v));
}

// out is write-once/never-read: NT store keeps it from evicting x from L3,
// so K3's re-read of x stays L3-resident.
__device__ __forceinline__ void nt_store4(float4* p, const float4& s) {
    __builtin_nontemporal_store(*reinterpret_cast<const v4f*>(&s),
                                reinterpret_cast<v4f*>(p));
}

// K1: per-(b, chunk) zero-init local scan (chunk 0: exact init s_{-1}=x0),
// writes only the chunk-end E_c. Double-buffered 8-deep register prefetch:
// next 8 loads issue while the current 8 feed the FMA chain -> continuous
// 8-16 independent 16 B loads in flight per lane, no LDS, no spill.
// Block: 256 threads = 2 b-rows x 128 float4 cols. Grid: (CC, BB/2).
__global__ __launch_bounds__(256) void es_chunk_ends(
    const float* __restrict__ x, const float* __restrict__ alpha,
    float* __restrict__ ends)
{
    const int c   = blockIdx.x;
    const int tid = threadIdx.x;
    const int b   = (blockIdx.y << 1) + (tid >> 7);
    const int d4  = tid & 127;

    const float4 al = reinterpret_cast<const float4*>(alpha)[d4];
    const float ax = sigmf(al.x), ay = sigmf(al.y), az = sigmf(al.z), aw = sigmf(al.w);
    const float fx = 1.0f - ax, fy = 1.0f - ay, fz = 1.0f - az, fw = 1.0f - aw;

    const float4* xp = reinterpret_cast<const float4*>(x)
                     + ((size_t)b * TT + (size_t)c * LL) * D4 + d4;

    float4 va[8], vb[8];
    #pragma unroll
    for (int k = 0; k < 8; ++k) va[k] = xp[(size_t)k * D4];

    float4 s;
    if (c == 0) { s = va[0]; }           // virtual s_{-1} = x_0 -> E_0 exact
    else        { s.x = s.y = s.z = s.w = 0.0f; }

    // Same FMA order as the R1 passing kernel -> bit-identical E_c.
    #pragma unroll
    for (int base = 0; base < LL; base += 16) {
        #pragma unroll
        for (int k = 0; k < 8; ++k) vb[k] = xp[(size_t)(base + 8 + k) * D4];
        #pragma unroll
        for (int k = 0; k < 8; ++k) {
            s.x = fmaf(ax, va[k].x, fx * s.x);
            s.y = fmaf(ay, va[k].y, fy * s.y);
            s.z = fmaf(az, va[k].z, fz * s.z);
            s.w = fmaf(aw, va[k].w, fw * s.w);
        }
        if (base + 16 < LL) {
            #pragma unroll
            for (int k = 0; k < 8; ++k) va[k] = xp[(size_t)(base + 16 + k) * D4];
        }
        #pragma unroll
        for (int k = 0; k < 8; ++k) {
            s.x = fmaf(ax, vb[k].x, fx * s.x);
            s.y = fmaf(ay, vb[k].y, fy * s.y);
            s.z = fmaf(az, vb[k].z, fz * s.z);
            s.w = fmaf(aw, vb[k].w, fw * s.w);
        }
    }

    reinterpret_cast<float4*>(ends)[((size_t)b * CC + c) * D4 + d4] = s;
}

// K3 (fused carry + final): per-block redundant lookback over E_0..E_{c-1}
// (ascending, 8-deep prefetch — same FMA order as R0's K2 -> bit-identical),
// then replay the chunk from the exact carry with double-buffered loads and
// NT stores. First 8 x-loads are issued BEFORE the lookback so the chunk-read
// latency hides under the lookback's dependent chain.
__global__ __launch_bounds__(256) void es_final_fused(
    const float* __restrict__ x, const float* __restrict__ alpha,
    const float* __restrict__ ends, float* __restrict__ out)
{
    const int c   = blockIdx.x;
    const int tid = threadIdx.x;
    const int b   = (blockIdx.y << 1) + (tid >> 7);
    const int d4  = tid & 127;

    const float4 al = reinterpret_cast<const float4*>(alpha)[d4];
    const float ax = sigmf(al.x), ay = sigmf(al.y), az = sigmf(al.z), aw = sigmf(al.w);
    const float fx = 1.0f - ax, fy = 1.0f - ay, fz = 1.0f - az, fw = 1.0f - aw;

    const size_t base_g = ((size_t)b * TT + (size_t)c * LL) * D4 + d4;
    const float4* xp = reinterpret_cast<const float4*>(x) + base_g;
    float4*       op = reinterpret_cast<float4*>(out) + base_g;

    // Early chunk prefetch: 8 independent loads in flight during the lookback.
    float4 va[8], vb[8];
    #pragma unroll
    for (int k = 0; k < 8; ++k) va[k] = xp[(size_t)k * D4];

    // Lookback: carry S_{c-1} = scan of E_0..E_{c-1} (exact, same order as R1).
    float4 s;
    if (c == 0) {
        s = va[0];                       // s_{-1} = x_0
    } else {
        float4 fL;
        fL.x = powf(fx, (float)LL);
        fL.y = powf(fy, (float)LL);
        fL.z = powf(fz, (float)LL);
        fL.w = powf(fw, (float)LL);

        const float4* e = reinterpret_cast<const float4*>(ends)
                        + (size_t)b * CC * D4 + d4;

        float4 S = e[0];                 // S_0 = E_0 (exact)
        int j = 1;
        for (; j + 8 <= c; j += 8) {     // 8-deep prefetch, FMA order unchanged
            float4 w[8];
            #pragma unroll
            for (int k = 0; k < 8; ++k) w[k] = e[(size_t)(j + k) * D4];
            #pragma unroll
            for (int k = 0; k < 8; ++k) {
                S.x = fmaf(fL.x, S.x, w[k].x);
                S.y = fmaf(fL.y, S.y, w[k].y);
                S.z = fmaf(fL.z, S.z, w[k].z);
                S.w = fmaf(fL.w, S.w, w[k].w);
            }
        }
        for (; j < c; ++j) {
            const float4 v = e[(size_t)j * D4];
            S.x = fmaf(fL.x, S.x, v.x);
            S.y = fmaf(fL.y, S.y, v.y);
            S.z = fmaf(fL.z, S.z, v.z);
            S.w = fmaf(fL.w, S.w, v.w);
        }
        s = S;                           // exact S_{c-1}
    }

    // Replay with double-buffered 8-deep loads; NT stores (same FMA order).
    #pragma unroll
    for (int base = 0; base < LL; base += 16) {
        #pragma unroll
        for (int k = 0; k < 8; ++k) vb[k] = xp[(size_t)(base + 8 + k) * D4];
        #pragma unroll
        for (int k = 0; k < 8; ++k) {
            s.x = fmaf(ax, va[k].x, fx * s.x);
            s.y = fmaf(ay, va[k].y, fy * s.y);
            s.z = fmaf(az, va[k].z, fz * s.z);
            s.w = fmaf(aw, va[k].w, fw * s.w);
            nt_store4(op + (size_t)(base + k) * D4, s);
        }
        if (base + 16 < LL) {
            #pragma unroll
            for (int k = 0; k < 8; ++k) va[k] = xp[(size_t)(base + 16 + k) * D4];
        }
        #pragma unroll
        for (int k = 0; k < 8; ++k) {
            s.x = fmaf(ax, vb[k].x, fx * s.x);
            s.y = fmaf(ay, vb[k].y, fy * s.y);
            s.z = fmaf(az, vb[k].z, fz * s.z);
            s.w = fmaf(aw, vb[k].w, fw * s.w);
            nt_store4(op + (size_t)(base + 8 + k) * D4, s);
        }
    }
}

// Fallback: full serial scan per (b, d4) column if ws is too small.
__global__ __launch_bounds__(256) void es_serial(
    const float* __restrict__ x, const float* __restrict__ alpha,
    float* __restrict__ out)
{
    const int g  = blockIdx.x * 256 + threadIdx.x;   // 0..2047
    const int b  = g >> 7;
    const int d4 = g & 127;

    const float4 al = reinterpret_cast<const float4*>(alpha)[d4];
    const float ax = sigmf(al.x), ay = sigmf(al.y), az = sigmf(al.z), aw = sigmf(al.w);
    const float fx = 1.0f - ax, fy = 1.0f - ay, fz = 1.0f - az, fw = 1.0f - aw;

    const float4* xp = reinterpret_cast<const float4*>(x) + (size_t)b * TT * D4 + d4;
    float4*       op = reinterpret_cast<float4*>(out) + (size_t)b * TT * D4 + d4;

    float4 s = xp[0];
    #pragma unroll 4
    for (int t = 0; t < TT; ++t) {
        const float4 v = xp[(size_t)t * D4];
        s.x = fmaf(ax, v.x, fx * s.x);
        s.y = fmaf(ay, v.y, fy * s.y);
        s.z = fmaf(az, v.z, fz * s.z);
        s.w = fmaf(aw, v.w, fw * s.w);
        op[(size_t)t * D4] = s;
    }
}

extern "C" void kernel_launch(void* const* d_in, const int* in_sizes, int n_in,
                              void* d_out, int out_size, void* d_ws, size_t ws_size,
                              hipStream_t stream)
{
    const float* x     = (const float*)d_in[0];
    const float* alpha = (const float*)d_in[1];
    float*       out   = (float*)d_out;

    const size_t need = (size_t)BB * CC * DD * sizeof(float);   // 4 MB ends buffer
    if (ws_size < need) {
        es_serial<<<dim3(8), 256, 0, stream>>>(x, alpha, out);
        return;
    }

    float* ends = (float*)d_ws;
    es_chunk_ends<<<dim3(CC, BB / 2), 256, 0, stream>>>(x, alpha, ends);
    es_final_fused<<<dim3(CC, BB / 2), 256, 0, stream>>>(x, alpha, ends, out);
}